// Round 4
// baseline (6564.726 us; speedup 1.0000x reference)
//
#include <hip/hip_runtime.h>
#include <cstdint>
#include <cstddef>
#include <math.h>

#define NROWS 65536
#define DIM   512
#define KCB   256
#define RPB   8     // rows per block in the per-stage kernels

// ---------------- Threefry-2x32 (jax partitionable; confirmed by R1 bulk match) ----------------
__host__ __device__ __forceinline__ uint32_t tf_rotl(uint32_t x, uint32_t r) {
  return (x << r) | (x >> (32u - r));
}
__host__ __device__ inline void tf2x32(uint32_t k0, uint32_t k1,
                                       uint32_t x0, uint32_t x1,
                                       uint32_t& o0, uint32_t& o1) {
  uint32_t k2 = k0 ^ k1 ^ 0x1BD11BDAu;
  x0 += k0; x1 += k1;
#define TF_R(r) { x0 += x1; x1 = tf_rotl(x1, r); x1 ^= x0; }
  TF_R(13) TF_R(15) TF_R(26) TF_R(6)
  x0 += k1; x1 += k2 + 1u;
  TF_R(17) TF_R(29) TF_R(16) TF_R(24)
  x0 += k2; x1 += k0 + 2u;
  TF_R(13) TF_R(15) TF_R(26) TF_R(6)
  x0 += k0; x1 += k1 + 3u;
  TF_R(17) TF_R(29) TF_R(16) TF_R(24)
  x0 += k1; x1 += k2 + 4u;
  TF_R(13) TF_R(15) TF_R(26) TF_R(6)
  x0 += k2; x1 += k0 + 5u;
#undef TF_R
  o0 = x0; o1 = x1;
}

// f32 gumbel, replicating np-f32: u from jax bits, then -log32(-log32(u)),
// each f32 log obtained by correctly-rounding the f64 log.
__device__ __forceinline__ float gumbel32(uint32_t k0, uint32_t k1, uint32_t j) {
  uint32_t o0, o1;
  tf2x32(k0, k1, 0u, j, o0, o1);
  uint32_t bits = o0 ^ o1;
  float f = __uint_as_float((bits >> 9) | 0x3f800000u) - 1.0f;
  if (f == 0.0f) f = 1.17549435e-38f;
  float t1 = (float)log((double)f);
  float t2 = (float)log((double)(-t1));
  return -t2;
}

__device__ __forceinline__ float exp32cr(float z) {
  return (float)exp((double)z);
}

// wave argmax: f32 value, smaller index wins ties (np first-occurrence)
__device__ __forceinline__ void argmax64(float& v, int& i) {
#pragma unroll
  for (int off = 32; off >= 1; off >>= 1) {
    float ov = __shfl_xor(v, off);
    int   oi = __shfl_xor(i, off);
    if (ov > v || (ov == v && oi < i)) { v = ov; i = oi; }
  }
}

// exact numpy pairwise_sum base case for n=128 (8-acc unroll + fixed combine tree)
__device__ float pw128(const float* a) {
  float r0 = a[0], r1 = a[1], r2 = a[2], r3 = a[3];
  float r4 = a[4], r5 = a[5], r6 = a[6], r7 = a[7];
  for (int i = 8; i < 128; i += 8) {
    r0 = __fadd_rn(r0, a[i + 0]); r1 = __fadd_rn(r1, a[i + 1]);
    r2 = __fadd_rn(r2, a[i + 2]); r3 = __fadd_rn(r3, a[i + 3]);
    r4 = __fadd_rn(r4, a[i + 4]); r5 = __fadd_rn(r5, a[i + 5]);
    r6 = __fadd_rn(r6, a[i + 6]); r7 = __fadd_rn(r7, a[i + 7]);
  }
  return __fadd_rn(__fadd_rn(__fadd_rn(r0, r1), __fadd_rn(r2, r3)),
                   __fadd_rn(__fadd_rn(r4, r5), __fadd_rn(r6, r7)));
}

// ---------------- cpd[i][d][k] = (C_i @ A_i)[k][d], seq-e FMA (BLAS order) ----------------
__global__ __launch_bounds__(256) void k_cproj(const float* __restrict__ C,
                                               const float* __restrict__ A,
                                               float* __restrict__ cpd) {
  const int i = blockIdx.x >> 6;
  const int d0 = (blockIdx.x & 63) * 8;
  const int t = threadIdx.x;          // t = k
  const float* Ai = A + (size_t)i * DIM * DIM;
  const float* Ci = C + (size_t)i * KCB * DIM;
  float acc[8] = {};
  for (int e = 0; e < DIM; ++e) {
    float cv = Ci[(size_t)t * DIM + e];
#pragma unroll
    for (int dd = 0; dd < 8; ++dd)
      acc[dd] = fmaf(cv, Ai[(size_t)e * DIM + d0 + dd], acc[dd]);
  }
#pragma unroll
  for (int dd = 0; dd < 8; ++dd)
    cpd[((size_t)i * DIM + d0 + dd) * KCB + t] = acc[dd];
}

// ---------------- Per-stage fused: xproj -> logits -> decisions -> out/sel/wstar ----------------
__global__ __launch_bounds__(256, 2) void k_decide(
    const float* __restrict__ X,      // current x (f32-faithful value)
    const float* __restrict__ Ai,     // W_att[i] [512][512]
    const float* __restrict__ cpdi,   // cproj^T for stage: [512 d][256 k]
    const float* __restrict__ Cbi,    // codebooks[i] [256][512]
    float* __restrict__ out,
    int* __restrict__ selG, float* __restrict__ wsG,
    uint32_t kh0, uint32_t kh1, uint32_t ks0, uint32_t ks1, int stage) {
  __shared__ float xrow[RPB * 512];   // reused as ssbuf[RPB*256] in phase 2
  __shared__ float xp[RPB * 512];
  __shared__ float lg[RPB * 256];
  __shared__ int selL[RPB]; __shared__ int idxL[RPB]; __shared__ float wsL[RPB];
  const int t = threadIdx.x;
  const int n0 = blockIdx.x * RPB;

  // phase 0a: stage x rows
#pragma unroll
  for (int r = 0; r < RPB; ++r) {
    xrow[r * 512 + t]       = X[(size_t)(n0 + r) * 512 + t];
    xrow[r * 512 + 256 + t] = X[(size_t)(n0 + r) * 512 + 256 + t];
  }
  __syncthreads();

  // phase 0b: xproj[n][d] = seq-e FMA of x[n][e]*A[e][d]  (BLAS sgemm order)
  {
    const int d0 = 2 * t;
    float acc[RPB][2];
#pragma unroll
    for (int r = 0; r < RPB; ++r) { acc[r][0] = 0.0f; acc[r][1] = 0.0f; }
    for (int e = 0; e < 512; ++e) {
      float2 av = *(const float2*)&Ai[(size_t)e * 512 + d0];
#pragma unroll
      for (int r = 0; r < RPB; ++r) {
        float xv = xrow[r * 512 + e];
        acc[r][0] = fmaf(xv, av.x, acc[r][0]);
        acc[r][1] = fmaf(xv, av.y, acc[r][1]);
      }
    }
#pragma unroll
    for (int r = 0; r < RPB; ++r) {
      xp[r * 512 + d0]     = acc[r][0];
      xp[r * 512 + d0 + 1] = acc[r][1];
    }
  }
  __syncthreads();

  // phase 1: logit[n][k] = seq-d (mul,add) of xp[n][d]*cpd[d][k]  (np.einsum order)
  {
    float acc[RPB] = {};
    for (int d = 0; d < 512; ++d) {
      float cv = cpdi[(size_t)d * 256 + t];
#pragma unroll
      for (int r = 0; r < RPB; ++r)
        acc[r] = __fadd_rn(acc[r], __fmul_rn(xp[r * 512 + d], cv));
    }
#pragma unroll
    for (int r = 0; r < RPB; ++r) lg[r * 256 + t] = acc[r];
  }
  __syncthreads();

  // phase 2: per-row decisions (wave owns 2 rows; lane c owns k = sub*64+c)
  float* ssbuf = xrow;   // xrow dead; reuse as exp buffer [RPB][256]
  const int c = t & 63;
#pragma unroll 1
  for (int rr = 0; rr < 2; ++rr) {
    const int r = (t >> 6) * 2 + rr;
    const int n = n0 + r;
    const uint32_t jb = (uint32_t)n * 256u;
    float l[4];
#pragma unroll
    for (int sub = 0; sub < 4; ++sub) l[sub] = lg[r * 256 + sub * 64 + c];
    // idx: first-max over f32 logits
    float bv = l[0]; int bi = c;
#pragma unroll
    for (int sub = 1; sub < 4; ++sub)
      if (l[sub] > bv) { bv = l[sub]; bi = sub * 64 + c; }
    argmax64(bv, bi);
    // hard sel: first-max over (l+g_hard)/0.9f
    float sv = 0.0f; int si = 0;
#pragma unroll
    for (int sub = 0; sub < 4; ++sub) {
      float g = gumbel32(kh0, kh1, jb + (uint32_t)(sub * 64 + c));
      float s = __fdiv_rn(__fadd_rn(l[sub], g), 0.9f);
      if (sub == 0 || s > sv) { sv = s; si = sub * 64 + c; }
    }
    argmax64(sv, si);
    // soft: scores, row max, exp (CR f32)
    float ssv[4];
#pragma unroll
    for (int sub = 0; sub < 4; ++sub) {
      float g = gumbel32(ks0, ks1, jb + (uint32_t)(sub * 64 + c));
      ssv[sub] = __fdiv_rn(__fadd_rn(l[sub], g), 0.9f);
    }
    float m = fmaxf(fmaxf(ssv[0], ssv[1]), fmaxf(ssv[2], ssv[3]));
#pragma unroll
    for (int off = 32; off >= 1; off >>= 1) m = fmaxf(m, __shfl_xor(m, off));
#pragma unroll
    for (int sub = 0; sub < 4; ++sub)
      ssbuf[r * 256 + sub * 64 + c] = exp32cr(__fsub_rn(ssv[sub], m));
    if (c == 0) { selL[r] = si; idxL[r] = bi; }
  }
  __syncthreads();

  // phase 2b: numpy-pairwise softmax denom, ws, wstar (one thread per row)
  if (t < RPB) {
    const int r = t, n = n0 + r;
    const float* a = &ssbuf[r * 256];
    float S = __fadd_rn(pw128(a), pw128(a + 128));
    int sel = selL[r];
    float ws = __fdiv_rn(a[sel], S);
    float wstar = __fadd_rn(__fsub_rn(1.0f, ws), ws);
    wsL[r] = wstar;
    selG[n] = sel; wsG[n] = wstar;
    out[(size_t)NROWS * DIM + (size_t)n * 4 + stage] = (float)idxL[r];
  }
  __syncthreads();

  // phase 3: out_sum accumulate: p = fl32(wstar * C[sel][col]), ref add order
#pragma unroll 1
  for (int r = 0; r < RPB; ++r) {
    const int n = n0 + r;
    const int sel = selL[r];
    const float w = wsL[r];
    const float* crow = Cbi + (size_t)sel * 512;
#pragma unroll
    for (int h = 0; h < 2; ++h) {
      int col = t + h * 256;
      float p = __fmul_rn(w, crow[col]);
      size_t o = (size_t)n * DIM + col;
      out[o] = (stage == 0) ? p : __fadd_rn(out[o], p);
    }
  }
}

// ---------------- x update: x_next = x - prev_out @ W_rnn (seq-d FMA; prev = fl32(w*C[sel])) ----------------
__global__ __launch_bounds__(256, 2) void k_xupd(
    const float* __restrict__ Xin, float* __restrict__ Xout,
    const float* __restrict__ Cbi, const float* __restrict__ Wr,
    const int* __restrict__ selG, const float* __restrict__ wsG) {
  __shared__ float p[RPB * 512];
  const int t = threadIdx.x;
  const int n0 = blockIdx.x * RPB;
#pragma unroll
  for (int r = 0; r < RPB; ++r) {
    const int n = n0 + r;
    const float* crow = Cbi + (size_t)selG[n] * 512;
    const float w = wsG[n];
    p[r * 512 + t]       = __fmul_rn(w, crow[t]);
    p[r * 512 + 256 + t] = __fmul_rn(w, crow[t + 256]);
  }
  __syncthreads();
  const int e0 = 2 * t;
  float acc[RPB][2];
#pragma unroll
  for (int r = 0; r < RPB; ++r) { acc[r][0] = 0.0f; acc[r][1] = 0.0f; }
  for (int d = 0; d < 512; ++d) {
    float2 wv = *(const float2*)&Wr[(size_t)d * 512 + e0];
#pragma unroll
    for (int r = 0; r < RPB; ++r) {
      float pv = p[r * 512 + d];
      acc[r][0] = fmaf(pv, wv.x, acc[r][0]);
      acc[r][1] = fmaf(pv, wv.y, acc[r][1]);
    }
  }
#pragma unroll
  for (int r = 0; r < RPB; ++r) {
    const size_t b = (size_t)(n0 + r) * 512 + e0;
    Xout[b]     = __fsub_rn(Xin[b],     acc[r][0]);
    Xout[b + 1] = __fsub_rn(Xin[b + 1], acc[r][1]);
  }
}

extern "C" void kernel_launch(void* const* d_in, const int* in_sizes, int n_in,
                              void* d_out, int out_size, void* d_ws, size_t ws_size,
                              hipStream_t stream) {
  const float* x  = (const float*)d_in[0];   // [65536,512]
  const float* Cb = (const float*)d_in[1];   // [4,256,512]
  const float* A  = (const float*)d_in[2];   // [4,512,512]
  const float* Wr = (const float*)d_in[3];   // [512,512]
  float* out = (float*)d_out;
  float* ws  = (float*)d_ws;

  float* cpd  = ws;                          // 4*512*256 = 524288 f (2 MB)
  float* xcur = ws + 524288;                 // 65536*512 = 33554432 f (134 MB)
  float* wsG  = ws + 524288 + 33554432;      // 65536 f
  int*   selG = (int*)(ws + 524288 + 33554432 + 65536);  // 65536 i32

  // keys: fold_in(key(42), i) -> split -> (k_soft = keys[0], k_hard = keys[1])
  uint32_t kh[4][2], ks[4][2];
  for (uint32_t i = 0; i < 4; ++i) {
    uint32_t f0, f1, a0, a1, b0, b1;
    tf2x32(0u, 42u, 0u, i, f0, f1);
    tf2x32(f0, f1, 0u, 0u, a0, a1);   // keys[0] -> k_soft
    tf2x32(f0, f1, 0u, 1u, b0, b1);   // keys[1] -> k_hard
    ks[i][0] = a0; ks[i][1] = a1;
    kh[i][0] = b0; kh[i][1] = b1;
  }

  k_cproj<<<dim3(256), dim3(256), 0, stream>>>(Cb, A, cpd);

  const int NB = NROWS / RPB;  // 8192
  for (int i = 0; i < 4; ++i) {
    const float* Xi = (i == 0) ? x : xcur;
    const float* Ai = A + (size_t)i * DIM * DIM;
    const float* cpdi = cpd + (size_t)i * DIM * KCB;
    const float* Cbi = Cb + (size_t)i * KCB * DIM;
    k_decide<<<dim3(NB), dim3(256), 0, stream>>>(Xi, Ai, cpdi, Cbi, out, selG, wsG,
                                                 kh[i][0], kh[i][1], ks[i][0], ks[i][1], i);
    if (i < 3)
      k_xupd<<<dim3(NB), dim3(256), 0, stream>>>(Xi, xcur, Cbi, Wr, selG, wsG);
  }
}